// Round 5
// baseline (424.889 us; speedup 1.0000x reference)
//
#include <hip/hip_runtime.h>

#define T_SEQ 2048
#define NHEAD 16
#define HS 64

typedef __bf16 bf16x8 __attribute__((ext_vector_type(8)));
typedef float f32x4 __attribute__((ext_vector_type(4)));

__device__ __forceinline__ unsigned short f2bf(float f) {
  union { float f; unsigned int u; } v; v.f = f;
  return (unsigned short)((v.u + 0x7fffu + ((v.u >> 16) & 1u)) >> 16);
}
__device__ __forceinline__ float bf2f(unsigned short h) {
  union { unsigned int u; float f; } v; v.u = ((unsigned int)h) << 16;
  return v.f;
}
__device__ __forceinline__ bf16x8 ld_bf8(const unsigned short* p) {
  return *(const bf16x8*)p;
}
__device__ __forceinline__ void st_bf8(unsigned short* p, bf16x8 v) {
  *(bf16x8*)p = v;
}
__device__ __forceinline__ bf16x8 cvt8(float4 a, float4 b) {
  bf16x8 r;
  r[0] = (__bf16)a.x; r[1] = (__bf16)a.y; r[2] = (__bf16)a.z; r[3] = (__bf16)a.w;
  r[4] = (__bf16)b.x; r[5] = (__bf16)b.y; r[6] = (__bf16)b.z; r[7] = (__bf16)b.w;
  return r;
}
// async global->LDS, 16B per lane; lds base must be wave-uniform (dest = base + lane*16)
__device__ __forceinline__ void gload_lds16(const void* g, void* l) {
  __builtin_amdgcn_global_load_lds(
      (const __attribute__((address_space(1))) unsigned int*)g,
      (__attribute__((address_space(3))) unsigned int*)l, 16, 0, 0);
}

// f32 -> bf16 (RNE), 8 elems/thread
__global__ __launch_bounds__(256) void cvt_bf16(const float* __restrict__ src,
                                                unsigned short* __restrict__ dst) {
  const size_t i = ((size_t)blockIdx.x * 256 + threadIdx.x) * 8;
  const float4 a = *(const float4*)(src + i);
  const float4 b = *(const float4*)(src + i + 4);
  st_bf8(dst + i, cvt8(a, b));
}

// C[m,n] = sum_k A[m,k]*B[n,k];  A bf16 [M][K]; B bf16 [N][K] (or f32 if bf32).
// m97 structure: 128x128 tile, BK=64, 4 waves, global_load_lds width-16 staging.
// mode 0: C row-major [M,N] f32.  mode 1: qkv scatter (N=3072) bf16 (V transposed).
__global__ __launch_bounds__(256, 2) void gemm_bt(
    const unsigned short* __restrict__ A, const void* __restrict__ Bv,
    float* __restrict__ Cout,
    unsigned short* __restrict__ qb, unsigned short* __restrict__ kb,
    unsigned short* __restrict__ vtb,
    int M, int N, int K, int bf32, int mode) {
  __shared__ unsigned short As[128 * 64];
  __shared__ unsigned short Bs[128 * 64];
  const int tid = threadIdx.x;
  const int wid = tid >> 6, lane = tid & 63;
  const int quad = lane >> 4, l16 = lane & 15;
  const int m0 = blockIdx.y * 128, n0 = blockIdx.x * 128;
  const int wm = (wid >> 1) * 64, wn = (wid & 1) * 64;
  const int srow = lane >> 3;
  const int scol = (lane & 7) * 8;
  const int brow = tid >> 3;
  const int bcol = (tid & 7) * 8;
  const unsigned short* Bh = (const unsigned short*)Bv;
  const float* Bf = (const float*)Bv;
  f32x4 acc[4][4] = {};
  const int nkt = K >> 6;
  for (int kt = 0; kt < nkt; ++kt) {
    const int k0 = kt * 64;
    #pragma unroll
    for (int j = 0; j < 4; ++j) {
      const int rr = wid * 32 + j * 8 + srow;
      gload_lds16(A + (size_t)(m0 + rr) * K + k0 + scol,
                  &As[(wid * 32 + j * 8) * 64]);
    }
    if (bf32) {
      bf16x8 bs8[4];
      #pragma unroll
      for (int j = 0; j < 4; ++j) {
        const float* p = Bf + (size_t)(n0 + j * 32 + brow) * K + k0 + bcol;
        bs8[j] = cvt8(*(const float4*)p, *(const float4*)(p + 4));
      }
      #pragma unroll
      for (int j = 0; j < 4; ++j)
        st_bf8(&Bs[(j * 32 + brow) * 64 + bcol], bs8[j]);   // prev-iter barrier protects
    } else {
      #pragma unroll
      for (int j = 0; j < 4; ++j) {
        const int rr = wid * 32 + j * 8 + srow;
        gload_lds16(Bh + (size_t)(n0 + rr) * K + k0 + scol,
                    &Bs[(wid * 32 + j * 8) * 64]);
      }
    }
    __syncthreads();
    #pragma unroll
    for (int ks = 0; ks < 2; ++ks) {
      bf16x8 af[4], bfr[4];
      #pragma unroll
      for (int mt = 0; mt < 4; ++mt)
        af[mt] = ld_bf8(&As[(wm + mt * 16 + l16) * 64 + ks * 32 + quad * 8]);
      #pragma unroll
      for (int nt = 0; nt < 4; ++nt)
        bfr[nt] = ld_bf8(&Bs[(wn + nt * 16 + l16) * 64 + ks * 32 + quad * 8]);
      #pragma unroll
      for (int mt = 0; mt < 4; ++mt)
        #pragma unroll
        for (int nt = 0; nt < 4; ++nt)
          acc[mt][nt] = __builtin_amdgcn_mfma_f32_16x16x32_bf16(af[mt], bfr[nt], acc[mt][nt], 0, 0, 0);
    }
    __syncthreads();
  }
  #pragma unroll
  for (int mt = 0; mt < 4; ++mt) {
    #pragma unroll
    for (int nt = 0; nt < 4; ++nt) {
      const int n = n0 + wn + nt * 16 + l16;
      #pragma unroll
      for (int r = 0; r < 4; ++r) {
        const int m = m0 + wm + mt * 16 + quad * 4 + r;
        if (mode == 0) {
          Cout[(size_t)m * N + n] = acc[mt][nt][r];
        } else {
          const unsigned short val = f2bf(acc[mt][nt][r]);
          const int b = m >> 11, t = m & (T_SEQ - 1);
          const int which = n >> 10, c = n & 1023;
          const int h = c >> 6, d = c & 63;
          const int bh = b * NHEAD + h;
          if (which == 0)      qb[((size_t)bh * T_SEQ + t) * HS + d] = val;
          else if (which == 1) kb[((size_t)bh * T_SEQ + t) * HS + d] = val;
          else                 vtb[((size_t)bh * HS + d) * T_SEQ + t] = val;  // V transposed
        }
      }
    }
  }
}

// Reference's rolled-RoPE.
__global__ __launch_bounds__(256, 1) void rope(unsigned short* __restrict__ qb,
                                               unsigned short* __restrict__ kb) {
  const int idx = blockIdx.x * 256 + threadIdx.x;
  unsigned short* buf = (idx < 65536 ? qb : kb) + (size_t)(idx & 65535) * HS;
  const int t = idx & (T_SEQ - 1);
  float x[64];
  #pragma unroll
  for (int j = 0; j < 64; ++j) x[j] = bf2f(buf[j]);
  __asm__ volatile("" ::: "memory");
  float c[32], s[32], er[32];
  #pragma unroll
  for (int i = 0; i < 32; ++i) {
    const float ang = (float)t * exp2f(-0.41524101186092029f * (float)i);
    c[i] = cosf(ang); s[i] = sinf(ang);
  }
  #pragma unroll
  for (int i = 0; i < 32; ++i)
    er[i] = x[2 * i] * c[i] - x[(2 * i + 63) & 63] * s[i];
  #pragma unroll
  for (int i = 0; i < 32; ++i) {
    const float ep = x[2 * i + 1] * c[i] + er[(i + 1) & 31] * s[i];
    buf[2 * i]     = f2bf(er[i]);
    buf[2 * i + 1] = f2bf(ep);
  }
}

// Flash attention: unit u = blockIdx.x*4 + wid (round-1/3-verified mapping).
// SINGLE change vs round 3 (which passed at 307us): __launch_bounds__(256, 8)
// forces <=64 VGPR -> 32 waves/CU (round-3 counters: VGPR=72 capped residency
// at 16 waves/CU, nullifying the k-split).  To fit: K/V fragments loaded in
// chunks of 2 tiles (8 transient regs, not 32) and alpha inlined (no alpha[4]).
// Accumulation order per S[t]/O[vg] (c=0 then c=1), masking, P-through-LDS,
// epilogues and split logic are UNCHANGED from round 3.
__global__ __launch_bounds__(256, 8) void attn(
    const unsigned short* __restrict__ qb, const unsigned short* __restrict__ kb,
    const unsigned short* __restrict__ vt, unsigned short* __restrict__ yb,
    float* __restrict__ Op, float* __restrict__ ml, int split) {
  __shared__ __bf16 Pl[4][16][72];
  const int wid = threadIdx.x >> 6;
  const int u = blockIdx.x * 4 + wid;  // 0..4095
  const int qi = 127 - (u >> 5);       // q-tile 0..127, longest first
  const int bh = u & 31;
  const int q0 = qi * 16;
  const int np = (qi >> 2) + 1;        // number of 64-wide k passes
  int p0 = 0, p1 = np;
  if (split) {
    const int half = np >> 1;
    if (blockIdx.y == 0) p1 = half;    // empty when np==1
    else                 p0 = half;
  }
  const int lane = threadIdx.x & 63;
  const int quad = lane >> 4, l16 = lane & 15;

  const unsigned short* qptr = qb + ((size_t)bh * T_SEQ + q0 + l16) * HS;
  bf16x8 aq[2];
  aq[0] = ld_bf8(qptr + quad * 8);
  aq[1] = ld_bf8(qptr + 32 + quad * 8);
  f32x4 O[4] = {};
  float m_i[4], l_i[4];
  #pragma unroll
  for (int r = 0; r < 4; ++r) { m_i[r] = -1e30f; l_i[r] = 0.f; }

  const unsigned short* kbase = kb + (size_t)bh * T_SEQ * HS;
  const unsigned short* vbase = vt + (size_t)bh * HS * T_SEQ;

  for (int p = p0; p < p1; ++p) {
    const int k0 = p * 64;
    f32x4 S[4] = {};
    // QK^T: per 32-wide kk-chunk c, K-tiles in pairs (8 transient regs)
    #pragma unroll
    for (int c = 0; c < 2; ++c) {
      #pragma unroll
      for (int th = 0; th < 2; ++th) {
        const bf16x8 b0 = ld_bf8(kbase + (size_t)(k0 + (th * 2 + 0) * 16 + l16) * HS + c * 32 + quad * 8);
        const bf16x8 b1 = ld_bf8(kbase + (size_t)(k0 + (th * 2 + 1) * 16 + l16) * HS + c * 32 + quad * 8);
        __builtin_amdgcn_s_setprio(1);
        S[th * 2 + 0] = __builtin_amdgcn_mfma_f32_16x16x32_bf16(aq[c], b0, S[th * 2 + 0], 0, 0, 0);
        S[th * 2 + 1] = __builtin_amdgcn_mfma_f32_16x16x32_bf16(aq[c], b1, S[th * 2 + 1], 0, 0, 0);
        __builtin_amdgcn_s_setprio(0);
      }
    }
    // online softmax over 64 k-cols, 4 q-rows per lane (quad*4+r); O rescale inline
    #pragma unroll
    for (int r = 0; r < 4; ++r) {
      const int row = q0 + quad * 4 + r;
      float s[4];
      #pragma unroll
      for (int t = 0; t < 4; ++t)
        s[t] = (k0 + t * 16 + l16 <= row) ? S[t][r] * 0.125f : -1e30f;
      float tm = fmaxf(fmaxf(s[0], s[1]), fmaxf(s[2], s[3]));
      #pragma unroll
      for (int off = 1; off < 16; off <<= 1) tm = fmaxf(tm, __shfl_xor(tm, off, 64));
      const float mnew = fmaxf(m_i[r], tm);
      const float alpha = __expf(m_i[r] - mnew);
      unsigned short h[4];
      float rs = 0.f;
      #pragma unroll
      for (int t = 0; t < 4; ++t) {
        h[t] = f2bf(__expf(s[t] - mnew));
        rs += bf2f(h[t]);                 // rounded-P denominator (matches numerator)
      }
      #pragma unroll
      for (int off = 1; off < 16; off <<= 1) rs += __shfl_xor(rs, off, 64);
      l_i[r] = l_i[r] * alpha + rs;
      m_i[r] = mnew;
      #pragma unroll
      for (int vg = 0; vg < 4; ++vg) O[vg][r] *= alpha;
      #pragma unroll
      for (int t = 0; t < 4; ++t)
        Pl[wid][quad * 4 + r][t * 16 + l16] = __builtin_bit_cast(__bf16, h[t]);
    }
    // PV: per 32-wide kk-chunk c, V-tiles in pairs (8 transient regs)
    #pragma unroll
    for (int c = 0; c < 2; ++c) {
      const bf16x8 pa = *(const bf16x8*)&Pl[wid][l16][c * 32 + quad * 8];
      #pragma unroll
      for (int vh = 0; vh < 2; ++vh) {
        const bf16x8 v0 = ld_bf8(vbase + (size_t)((vh * 2 + 0) * 16 + l16) * T_SEQ + k0 + c * 32 + quad * 8);
        const bf16x8 v1 = ld_bf8(vbase + (size_t)((vh * 2 + 1) * 16 + l16) * T_SEQ + k0 + c * 32 + quad * 8);
        __builtin_amdgcn_s_setprio(1);
        O[vh * 2 + 0] = __builtin_amdgcn_mfma_f32_16x16x32_bf16(pa, v0, O[vh * 2 + 0], 0, 0, 0);
        O[vh * 2 + 1] = __builtin_amdgcn_mfma_f32_16x16x32_bf16(pa, v1, O[vh * 2 + 1], 0, 0, 0);
        __builtin_amdgcn_s_setprio(0);
      }
    }
  }
  if (!split) {
    const int b = bh >> 4, h = bh & 15;
    #pragma unroll
    for (int r = 0; r < 4; ++r) {
      const float inv = 1.0f / fmaxf(l_i[r], 1e-30f);
      const int row = q0 + quad * 4 + r;
      #pragma unroll
      for (int vg = 0; vg < 4; ++vg)
        yb[((size_t)b * T_SEQ + row) * 1024 + h * HS + vg * 16 + l16] = f2bf(O[vg][r] * inv);
    }
  } else {
    // partials at physical row index: [seg][bh][t][d]
    const size_t base = ((size_t)blockIdx.y * 32 + bh) * T_SEQ;
    #pragma unroll
    for (int r = 0; r < 4; ++r) {
      const int row = q0 + quad * 4 + r;
      #pragma unroll
      for (int vg = 0; vg < 4; ++vg)
        Op[(base + row) * 64 + vg * 16 + l16] = O[vg][r];
      if (l16 == 0) {
        ml[(base + row) * 2]     = m_i[r];
        ml[(base + row) * 2 + 1] = l_i[r];
      }
    }
  }
}

// Merge the 2 k-segment partials per physical row (bh, t):
//   m=max, l = sum l_s*e^{m_s-m}, y = (sum O_s*e^{m_s-m})/l.
// Empty seg0 (m=-1e30, l=0, O=0) contributes exactly zero.
__global__ __launch_bounds__(64) void combine(const float* __restrict__ Op,
                                              const float* __restrict__ ml,
                                              unsigned short* __restrict__ yb) {
  const int w = blockIdx.x;            // 0..4095
  const int bh = w >> 7;               // 0..31
  const int t0 = (w & 127) * 16;
  const int lane = threadIdx.x;        // d 0..63
  const int b = bh >> 4, h = bh & 15;
  const size_t s0 = (size_t)bh * T_SEQ;
  const size_t s1 = (size_t)(32 + bh) * T_SEQ;
  for (int r = 0; r < 16; ++r) {
    const int t = t0 + r;
    const float m0 = ml[(s0 + t) * 2], l0 = ml[(s0 + t) * 2 + 1];
    const float m1 = ml[(s1 + t) * 2], l1 = ml[(s1 + t) * 2 + 1];
    const float m = fmaxf(m0, m1);
    const float a0 = __expf(m0 - m), a1 = __expf(m1 - m);
    const float l = l0 * a0 + l1 * a1;
    const float o = Op[(s0 + t) * 64 + lane] * a0 +
                    Op[(s1 + t) * 64 + lane] * a1;
    yb[((size_t)b * T_SEQ + t) * 1024 + h * HS + lane] = f2bf(o / fmaxf(l, 1e-30f));
  }
}

extern "C" void kernel_launch(void* const* d_in, const int* in_sizes, int n_in,
                              void* d_out, int out_size, void* d_ws, size_t ws_size,
                              hipStream_t stream) {
  const float* x      = (const float*)d_in[0];
  const float* w_attn = (const float*)d_in[1];
  const float* w_proj = (const float*)d_in[2];
  float* out = (float*)d_out;
  // ws layout: qb@0(8Mi) kb@8Mi vt@16Mi yb/xb@24Mi wab@32Mi(6Mi) wpb@38Mi(2Mi)
  // Opart@40Mi(32Mi) mlb@72Mi(1Mi).  No aliasing except xb/yb (sequential).
  unsigned short* qb = (unsigned short*)d_ws;
  unsigned short* kb = qb + (size_t)4194304;
  unsigned short* vt = kb + (size_t)4194304;
  unsigned short* yb = vt + (size_t)4194304;
  unsigned short* xb = yb;                      // consumed by gemm1 before attn writes yb
  unsigned short* wab = yb + (size_t)4194304;
  unsigned short* wpb = wab + (size_t)3145728;
  float* Opart = (float*)((char*)d_ws + ((size_t)40 << 20));
  float* mlb   = (float*)((char*)d_ws + ((size_t)72 << 20));
  const int bigw = ws_size >= ((size_t)40 << 20);   // bf16 weights staged
  const int bigs = ws_size >= ((size_t)74 << 20);   // + k-split attn partials

  // 0) pre-convert operands to bf16
  cvt_bf16<<<dim3(2048), 256, 0, stream>>>(x, xb);
  if (bigw) {
    cvt_bf16<<<dim3(1536), 256, 0, stream>>>(w_attn, wab);
    cvt_bf16<<<dim3(512), 256, 0, stream>>>(w_proj, wpb);
  }
  // 1) qkv = x @ w_attn^T -> q/k layouts, V transposed scatter (round-1/3-verified)
  gemm_bt<<<dim3(24, 32), 256, 0, stream>>>(
      xb, bigw ? (const void*)wab : (const void*)w_attn, nullptr,
      qb, kb, vt, 4096, 3072, 1024, bigw ? 0 : 1, 1);
  // 2) RoPE in-place on q, k
  rope<<<dim3(512), 256, 0, stream>>>(qb, kb);
  // 3) causal flash attention
  if (bigs) {
    attn<<<dim3(1024, 2), 256, 0, stream>>>(qb, kb, vt, nullptr, Opart, mlb, 1);
    combine<<<dim3(4096), 64, 0, stream>>>(Opart, mlb, yb);
  } else {
    attn<<<dim3(1024), 256, 0, stream>>>(qb, kb, vt, yb, nullptr, nullptr, 0);
  }
  // 4) out = y(bf16) @ w_proj^T -> f32
  gemm_bt<<<dim3(8, 32), 256, 0, stream>>>(
      yb, bigw ? (const void*)wpb : (const void*)w_proj, out,
      nullptr, nullptr, nullptr, 4096, 1024, 1024, bigw ? 0 : 1, 0);
}

// Round 8
// 298.935 us; speedup vs baseline: 1.4213x; 1.4213x over previous
//
#include <hip/hip_runtime.h>

#define T_SEQ 2048
#define NHEAD 16
#define HS 64

typedef __bf16 bf16x8 __attribute__((ext_vector_type(8)));
typedef float f32x4 __attribute__((ext_vector_type(4)));

__device__ __forceinline__ unsigned short f2bf(float f) {
  union { float f; unsigned int u; } v; v.f = f;
  return (unsigned short)((v.u + 0x7fffu + ((v.u >> 16) & 1u)) >> 16);
}
__device__ __forceinline__ float bf2f(unsigned short h) {
  union { unsigned int u; float f; } v; v.u = ((unsigned int)h) << 16;
  return v.f;
}
__device__ __forceinline__ bf16x8 ld_bf8(const unsigned short* p) {
  return *(const bf16x8*)p;
}
__device__ __forceinline__ void st_bf8(unsigned short* p, bf16x8 v) {
  *(bf16x8*)p = v;
}
__device__ __forceinline__ bf16x8 cvt8(float4 a, float4 b) {
  bf16x8 r;
  r[0] = (__bf16)a.x; r[1] = (__bf16)a.y; r[2] = (__bf16)a.z; r[3] = (__bf16)a.w;
  r[4] = (__bf16)b.x; r[5] = (__bf16)b.y; r[6] = (__bf16)b.z; r[7] = (__bf16)b.w;
  return r;
}
// async global->LDS, 16B per lane; lds base must be wave-uniform (dest = base + lane*16)
__device__ __forceinline__ void gload_lds16(const void* g, void* l) {
  __builtin_amdgcn_global_load_lds(
      (const __attribute__((address_space(1))) unsigned int*)g,
      (__attribute__((address_space(3))) unsigned int*)l, 16, 0, 0);
}

// f32 -> bf16 (RNE), 8 elems/thread
__global__ __launch_bounds__(256) void cvt_bf16(const float* __restrict__ src,
                                                unsigned short* __restrict__ dst) {
  const size_t i = ((size_t)blockIdx.x * 256 + threadIdx.x) * 8;
  const float4 a = *(const float4*)(src + i);
  const float4 b = *(const float4*)(src + i + 4);
  st_bf8(dst + i, cvt8(a, b));
}

// C[m,n] = sum_k A[m,k]*B[n,k];  A bf16 [M][K]; B bf16 [N][K] (or f32 if bf32).
// m97 structure: 128x128 tile, BK=64, 4 waves, global_load_lds width-16 staging.
// mode 0: C row-major [M,N] f32.  mode 1: qkv scatter (N=3072) bf16 (V transposed).
__global__ __launch_bounds__(256, 2) void gemm_bt(
    const unsigned short* __restrict__ A, const void* __restrict__ Bv,
    float* __restrict__ Cout,
    unsigned short* __restrict__ qb, unsigned short* __restrict__ kb,
    unsigned short* __restrict__ vtb,
    int M, int N, int K, int bf32, int mode) {
  __shared__ unsigned short As[128 * 64];
  __shared__ unsigned short Bs[128 * 64];
  const int tid = threadIdx.x;
  const int wid = tid >> 6, lane = tid & 63;
  const int quad = lane >> 4, l16 = lane & 15;
  const int m0 = blockIdx.y * 128, n0 = blockIdx.x * 128;
  const int wm = (wid >> 1) * 64, wn = (wid & 1) * 64;
  const int srow = lane >> 3;
  const int scol = (lane & 7) * 8;
  const int brow = tid >> 3;
  const int bcol = (tid & 7) * 8;
  const unsigned short* Bh = (const unsigned short*)Bv;
  const float* Bf = (const float*)Bv;
  f32x4 acc[4][4] = {};
  const int nkt = K >> 6;
  for (int kt = 0; kt < nkt; ++kt) {
    const int k0 = kt * 64;
    #pragma unroll
    for (int j = 0; j < 4; ++j) {
      const int rr = wid * 32 + j * 8 + srow;
      gload_lds16(A + (size_t)(m0 + rr) * K + k0 + scol,
                  &As[(wid * 32 + j * 8) * 64]);
    }
    if (bf32) {
      bf16x8 bs8[4];
      #pragma unroll
      for (int j = 0; j < 4; ++j) {
        const float* p = Bf + (size_t)(n0 + j * 32 + brow) * K + k0 + bcol;
        bs8[j] = cvt8(*(const float4*)p, *(const float4*)(p + 4));
      }
      #pragma unroll
      for (int j = 0; j < 4; ++j)
        st_bf8(&Bs[(j * 32 + brow) * 64 + bcol], bs8[j]);   // prev-iter barrier protects
    } else {
      #pragma unroll
      for (int j = 0; j < 4; ++j) {
        const int rr = wid * 32 + j * 8 + srow;
        gload_lds16(Bh + (size_t)(n0 + rr) * K + k0 + scol,
                    &Bs[(wid * 32 + j * 8) * 64]);
      }
    }
    __syncthreads();
    #pragma unroll
    for (int ks = 0; ks < 2; ++ks) {
      bf16x8 af[4], bfr[4];
      #pragma unroll
      for (int mt = 0; mt < 4; ++mt)
        af[mt] = ld_bf8(&As[(wm + mt * 16 + l16) * 64 + ks * 32 + quad * 8]);
      #pragma unroll
      for (int nt = 0; nt < 4; ++nt)
        bfr[nt] = ld_bf8(&Bs[(wn + nt * 16 + l16) * 64 + ks * 32 + quad * 8]);
      #pragma unroll
      for (int mt = 0; mt < 4; ++mt)
        #pragma unroll
        for (int nt = 0; nt < 4; ++nt)
          acc[mt][nt] = __builtin_amdgcn_mfma_f32_16x16x32_bf16(af[mt], bfr[nt], acc[mt][nt], 0, 0, 0);
    }
    __syncthreads();
  }
  #pragma unroll
  for (int mt = 0; mt < 4; ++mt) {
    #pragma unroll
    for (int nt = 0; nt < 4; ++nt) {
      const int n = n0 + wn + nt * 16 + l16;
      #pragma unroll
      for (int r = 0; r < 4; ++r) {
        const int m = m0 + wm + mt * 16 + quad * 4 + r;
        if (mode == 0) {
          Cout[(size_t)m * N + n] = acc[mt][nt][r];
        } else {
          const unsigned short val = f2bf(acc[mt][nt][r]);
          const int b = m >> 11, t = m & (T_SEQ - 1);
          const int which = n >> 10, c = n & 1023;
          const int h = c >> 6, d = c & 63;
          const int bh = b * NHEAD + h;
          if (which == 0)      qb[((size_t)bh * T_SEQ + t) * HS + d] = val;
          else if (which == 1) kb[((size_t)bh * T_SEQ + t) * HS + d] = val;
          else                 vtb[((size_t)bh * HS + d) * T_SEQ + t] = val;  // V transposed
        }
      }
    }
  }
}

// Reference's rolled-RoPE.  SCALAR form, verbatim from R1/R3/R5 (all passed).
// (R7's bf16x8-vectorized rope is a suspect in the 0.554 failure -- reverted.)
__global__ __launch_bounds__(256, 1) void rope(unsigned short* __restrict__ qb,
                                               unsigned short* __restrict__ kb) {
  const int idx = blockIdx.x * 256 + threadIdx.x;
  unsigned short* buf = (idx < 65536 ? qb : kb) + (size_t)(idx & 65535) * HS;
  const int t = idx & (T_SEQ - 1);
  float x[64];
  #pragma unroll
  for (int j = 0; j < 64; ++j) x[j] = bf2f(buf[j]);
  __asm__ volatile("" ::: "memory");
  float c[32], s[32], er[32];
  #pragma unroll
  for (int i = 0; i < 32; ++i) {
    const float ang = (float)t * exp2f(-0.41524101186092029f * (float)i);
    c[i] = cosf(ang); s[i] = sinf(ang);
  }
  #pragma unroll
  for (int i = 0; i < 32; ++i)
    er[i] = x[2 * i] * c[i] - x[(2 * i + 63) & 63] * s[i];
  #pragma unroll
  for (int i = 0; i < 32; ++i) {
    const float ep = x[2 * i + 1] * c[i] + er[(i + 1) & 31] * s[i];
    buf[2 * i]     = f2bf(er[i]);
    buf[2 * i + 1] = f2bf(ep);
  }
}

// ---- Flash attention, k-SPLIT kernel (hot path) ----
// Grid (1024, 2): unit u = blockIdx.x*4 + wid (R1/R3/R5-verified mapping);
// blockIdx.y = k-segment (0: [0,np/2) -- may be empty; 1: [np/2,np)).
// Dedicated split-only kernel: no flag branch, no yb epilogue, no alpha[] --
// engineered (NOT forced: R5's __launch_bounds__(256,8) caused VGPR=32 + 650MB
// scratch spill, 265us) to land naturally <=64 VGPR so 32 waves/CU are resident
// (m69 cliff: 64/128/256).  Inner loop identical to R5's verified body.
// Partials at physical row index [seg][bh][t][d].
__global__ __launch_bounds__(256) void attn_split(
    const unsigned short* __restrict__ qb, const unsigned short* __restrict__ kb,
    const unsigned short* __restrict__ vt,
    float* __restrict__ Op, float* __restrict__ ml) {
  __shared__ __bf16 Pl[4][16][72];
  const int wid = threadIdx.x >> 6;
  const int u = blockIdx.x * 4 + wid;  // 0..4095
  const int qi = 127 - (u >> 5);       // q-tile 0..127, longest first
  const int bh = u & 31;
  const int q0 = qi * 16;
  const int np = (qi >> 2) + 1;        // number of 64-wide k passes
  const int half = np >> 1;
  const int p0 = (blockIdx.y == 0) ? 0 : half;
  const int p1 = (blockIdx.y == 0) ? half : np;
  const int lane = threadIdx.x & 63;
  const int quad = lane >> 4, l16 = lane & 15;

  const unsigned short* qptr = qb + ((size_t)bh * T_SEQ + q0 + l16) * HS;
  bf16x8 aq[2];
  aq[0] = ld_bf8(qptr + quad * 8);
  aq[1] = ld_bf8(qptr + 32 + quad * 8);
  f32x4 O[4] = {};
  float m_i[4], l_i[4];
  #pragma unroll
  for (int r = 0; r < 4; ++r) { m_i[r] = -1e30f; l_i[r] = 0.f; }

  const unsigned short* kbase = kb + (size_t)bh * T_SEQ * HS;
  const unsigned short* vbase = vt + (size_t)bh * HS * T_SEQ;

  for (int p = p0; p < p1; ++p) {
    const int k0 = p * 64;
    f32x4 S[4] = {};
    // QK^T: per 32-wide kk-chunk c, K-tiles in pairs (8 transient regs)
    #pragma unroll
    for (int c = 0; c < 2; ++c) {
      #pragma unroll
      for (int th = 0; th < 2; ++th) {
        const bf16x8 b0 = ld_bf8(kbase + (size_t)(k0 + (th * 2 + 0) * 16 + l16) * HS + c * 32 + quad * 8);
        const bf16x8 b1 = ld_bf8(kbase + (size_t)(k0 + (th * 2 + 1) * 16 + l16) * HS + c * 32 + quad * 8);
        __builtin_amdgcn_s_setprio(1);
        S[th * 2 + 0] = __builtin_amdgcn_mfma_f32_16x16x32_bf16(aq[c], b0, S[th * 2 + 0], 0, 0, 0);
        S[th * 2 + 1] = __builtin_amdgcn_mfma_f32_16x16x32_bf16(aq[c], b1, S[th * 2 + 1], 0, 0, 0);
        __builtin_amdgcn_s_setprio(0);
      }
    }
    // online softmax over 64 k-cols, 4 q-rows per lane (quad*4+r); O rescale inline
    #pragma unroll
    for (int r = 0; r < 4; ++r) {
      const int row = q0 + quad * 4 + r;
      float s[4];
      #pragma unroll
      for (int t = 0; t < 4; ++t)
        s[t] = (k0 + t * 16 + l16 <= row) ? S[t][r] * 0.125f : -1e30f;
      float tm = fmaxf(fmaxf(s[0], s[1]), fmaxf(s[2], s[3]));
      #pragma unroll
      for (int off = 1; off < 16; off <<= 1) tm = fmaxf(tm, __shfl_xor(tm, off, 64));
      const float mnew = fmaxf(m_i[r], tm);
      const float alpha = __expf(m_i[r] - mnew);
      unsigned short h[4];
      float rs = 0.f;
      #pragma unroll
      for (int t = 0; t < 4; ++t) {
        h[t] = f2bf(__expf(s[t] - mnew));
        rs += bf2f(h[t]);                 // rounded-P denominator (matches numerator)
      }
      #pragma unroll
      for (int off = 1; off < 16; off <<= 1) rs += __shfl_xor(rs, off, 64);
      l_i[r] = l_i[r] * alpha + rs;
      m_i[r] = mnew;
      #pragma unroll
      for (int vg = 0; vg < 4; ++vg) O[vg][r] *= alpha;
      #pragma unroll
      for (int t = 0; t < 4; ++t)
        Pl[wid][quad * 4 + r][t * 16 + l16] = __builtin_bit_cast(__bf16, h[t]);
    }
    // PV: per 32-wide kk-chunk c, V-tiles in pairs (8 transient regs)
    #pragma unroll
    for (int c = 0; c < 2; ++c) {
      const bf16x8 pa = *(const bf16x8*)&Pl[wid][l16][c * 32 + quad * 8];
      #pragma unroll
      for (int vh = 0; vh < 2; ++vh) {
        const bf16x8 v0 = ld_bf8(vbase + (size_t)((vh * 2 + 0) * 16 + l16) * T_SEQ + k0 + c * 32 + quad * 8);
        const bf16x8 v1 = ld_bf8(vbase + (size_t)((vh * 2 + 1) * 16 + l16) * T_SEQ + k0 + c * 32 + quad * 8);
        __builtin_amdgcn_s_setprio(1);
        O[vh * 2 + 0] = __builtin_amdgcn_mfma_f32_16x16x32_bf16(pa, v0, O[vh * 2 + 0], 0, 0, 0);
        O[vh * 2 + 1] = __builtin_amdgcn_mfma_f32_16x16x32_bf16(pa, v1, O[vh * 2 + 1], 0, 0, 0);
        __builtin_amdgcn_s_setprio(0);
      }
    }
  }
  // partials at physical row index: [seg][bh][t][d]
  const size_t base = ((size_t)blockIdx.y * 32 + bh) * T_SEQ;
  #pragma unroll
  for (int r = 0; r < 4; ++r) {
    const int row = q0 + quad * 4 + r;
    #pragma unroll
    for (int vg = 0; vg < 4; ++vg)
      Op[(base + row) * 64 + vg * 16 + l16] = O[vg][r];
    if (l16 == 0) {
      ml[(base + row) * 2]     = m_i[r];
      ml[(base + row) * 2 + 1] = l_i[r];
    }
  }
}

// ---- Non-split fallback (small-ws only): same body, yb epilogue ----
__global__ __launch_bounds__(256) void attn_full(
    const unsigned short* __restrict__ qb, const unsigned short* __restrict__ kb,
    const unsigned short* __restrict__ vt, unsigned short* __restrict__ yb) {
  __shared__ __bf16 Pl[4][16][72];
  const int wid = threadIdx.x >> 6;
  const int u = blockIdx.x * 4 + wid;
  const int qi = 127 - (u >> 5);
  const int bh = u & 31;
  const int q0 = qi * 16;
  const int np = (qi >> 2) + 1;
  const int lane = threadIdx.x & 63;
  const int quad = lane >> 4, l16 = lane & 15;
  const unsigned short* qptr = qb + ((size_t)bh * T_SEQ + q0 + l16) * HS;
  bf16x8 aq[2];
  aq[0] = ld_bf8(qptr + quad * 8);
  aq[1] = ld_bf8(qptr + 32 + quad * 8);
  f32x4 O[4] = {};
  float m_i[4], l_i[4];
  #pragma unroll
  for (int r = 0; r < 4; ++r) { m_i[r] = -1e30f; l_i[r] = 0.f; }
  const unsigned short* kbase = kb + (size_t)bh * T_SEQ * HS;
  const unsigned short* vbase = vt + (size_t)bh * HS * T_SEQ;
  for (int p = 0; p < np; ++p) {
    const int k0 = p * 64;
    f32x4 S[4] = {};
    #pragma unroll
    for (int c = 0; c < 2; ++c) {
      #pragma unroll
      for (int th = 0; th < 2; ++th) {
        const bf16x8 b0 = ld_bf8(kbase + (size_t)(k0 + (th * 2 + 0) * 16 + l16) * HS + c * 32 + quad * 8);
        const bf16x8 b1 = ld_bf8(kbase + (size_t)(k0 + (th * 2 + 1) * 16 + l16) * HS + c * 32 + quad * 8);
        __builtin_amdgcn_s_setprio(1);
        S[th * 2 + 0] = __builtin_amdgcn_mfma_f32_16x16x32_bf16(aq[c], b0, S[th * 2 + 0], 0, 0, 0);
        S[th * 2 + 1] = __builtin_amdgcn_mfma_f32_16x16x32_bf16(aq[c], b1, S[th * 2 + 1], 0, 0, 0);
        __builtin_amdgcn_s_setprio(0);
      }
    }
    #pragma unroll
    for (int r = 0; r < 4; ++r) {
      const int row = q0 + quad * 4 + r;
      float s[4];
      #pragma unroll
      for (int t = 0; t < 4; ++t)
        s[t] = (k0 + t * 16 + l16 <= row) ? S[t][r] * 0.125f : -1e30f;
      float tm = fmaxf(fmaxf(s[0], s[1]), fmaxf(s[2], s[3]));
      #pragma unroll
      for (int off = 1; off < 16; off <<= 1) tm = fmaxf(tm, __shfl_xor(tm, off, 64));
      const float mnew = fmaxf(m_i[r], tm);
      const float alpha = __expf(m_i[r] - mnew);
      unsigned short h[4];
      float rs = 0.f;
      #pragma unroll
      for (int t = 0; t < 4; ++t) {
        h[t] = f2bf(__expf(s[t] - mnew));
        rs += bf2f(h[t]);
      }
      #pragma unroll
      for (int off = 1; off < 16; off <<= 1) rs += __shfl_xor(rs, off, 64);
      l_i[r] = l_i[r] * alpha + rs;
      m_i[r] = mnew;
      #pragma unroll
      for (int vg = 0; vg < 4; ++vg) O[vg][r] *= alpha;
      #pragma unroll
      for (int t = 0; t < 4; ++t)
        Pl[wid][quad * 4 + r][t * 16 + l16] = __builtin_bit_cast(__bf16, h[t]);
    }
    #pragma unroll
    for (int c = 0; c < 2; ++c) {
      const bf16x8 pa = *(const bf16x8*)&Pl[wid][l16][c * 32 + quad * 8];
      #pragma unroll
      for (int vh = 0; vh < 2; ++vh) {
        const bf16x8 v0 = ld_bf8(vbase + (size_t)((vh * 2 + 0) * 16 + l16) * T_SEQ + k0 + c * 32 + quad * 8);
        const bf16x8 v1 = ld_bf8(vbase + (size_t)((vh * 2 + 1) * 16 + l16) * T_SEQ + k0 + c * 32 + quad * 8);
        __builtin_amdgcn_s_setprio(1);
        O[vh * 2 + 0] = __builtin_amdgcn_mfma_f32_16x16x32_bf16(pa, v0, O[vh * 2 + 0], 0, 0, 0);
        O[vh * 2 + 1] = __builtin_amdgcn_mfma_f32_16x16x32_bf16(pa, v1, O[vh * 2 + 1], 0, 0, 0);
        __builtin_amdgcn_s_setprio(0);
      }
    }
  }
  const int b = bh >> 4, h = bh & 15;
  #pragma unroll
  for (int r = 0; r < 4; ++r) {
    const float inv = 1.0f / fmaxf(l_i[r], 1e-30f);
    const int row = q0 + quad * 4 + r;
    #pragma unroll
    for (int vg = 0; vg < 4; ++vg)
      yb[((size_t)b * T_SEQ + row) * 1024 + h * HS + vg * 16 + l16] = f2bf(O[vg][r] * inv);
  }
}

// Merge the 2 k-segment partials per physical row (bh, t):
//   m=max, l = sum l_s*e^{m_s-m}, y = (sum O_s*e^{m_s-m})/l.
// Empty seg0 (m=-1e30, l=0, O=0) contributes exactly zero.
__global__ __launch_bounds__(64) void combine(const float* __restrict__ Op,
                                              const float* __restrict__ ml,
                                              unsigned short* __restrict__ yb) {
  const int w = blockIdx.x;            // 0..4095
  const int bh = w >> 7;               // 0..31
  const int t0 = (w & 127) * 16;
  const int lane = threadIdx.x;        // d 0..63
  const int b = bh >> 4, h = bh & 15;
  const size_t s0 = (size_t)bh * T_SEQ;
  const size_t s1 = (size_t)(32 + bh) * T_SEQ;
  for (int r = 0; r < 16; ++r) {
    const int t = t0 + r;
    const float m0 = ml[(s0 + t) * 2], l0 = ml[(s0 + t) * 2 + 1];
    const float m1 = ml[(s1 + t) * 2], l1 = ml[(s1 + t) * 2 + 1];
    const float m = fmaxf(m0, m1);
    const float a0 = __expf(m0 - m), a1 = __expf(m1 - m);
    const float l = l0 * a0 + l1 * a1;
    const float o = Op[(s0 + t) * 64 + lane] * a0 +
                    Op[(s1 + t) * 64 + lane] * a1;
    yb[((size_t)b * T_SEQ + t) * 1024 + h * HS + lane] = f2bf(o / fmaxf(l, 1e-30f));
  }
}

extern "C" void kernel_launch(void* const* d_in, const int* in_sizes, int n_in,
                              void* d_out, int out_size, void* d_ws, size_t ws_size,
                              hipStream_t stream) {
  const float* x      = (const float*)d_in[0];
  const float* w_attn = (const float*)d_in[1];
  const float* w_proj = (const float*)d_in[2];
  float* out = (float*)d_out;
  // ws layout: qb@0(8Mi) kb@8Mi vt@16Mi yb/xb@24Mi wab@32Mi(6Mi) wpb@38Mi(2Mi)
  // Opart@40Mi(32Mi) mlb@72Mi(1Mi).  No aliasing except xb/yb (sequential).
  unsigned short* qb = (unsigned short*)d_ws;
  unsigned short* kb = qb + (size_t)4194304;
  unsigned short* vt = kb + (size_t)4194304;
  unsigned short* yb = vt + (size_t)4194304;
  unsigned short* xb = yb;                      // consumed by gemm1 before attn writes yb
  unsigned short* wab = yb + (size_t)4194304;
  unsigned short* wpb = wab + (size_t)3145728;
  float* Opart = (float*)((char*)d_ws + ((size_t)40 << 20));
  float* mlb   = (float*)((char*)d_ws + ((size_t)72 << 20));
  const int bigw = ws_size >= ((size_t)40 << 20);   // bf16 weights staged
  const int bigs = ws_size >= ((size_t)74 << 20);   // + k-split attn partials

  // 0) pre-convert operands to bf16
  cvt_bf16<<<dim3(2048), 256, 0, stream>>>(x, xb);
  if (bigw) {
    cvt_bf16<<<dim3(1536), 256, 0, stream>>>(w_attn, wab);
    cvt_bf16<<<dim3(512), 256, 0, stream>>>(w_proj, wpb);
  }
  // 1) qkv = x @ w_attn^T -> q/k layouts, V transposed scatter (verified)
  gemm_bt<<<dim3(24, 32), 256, 0, stream>>>(
      xb, bigw ? (const void*)wab : (const void*)w_attn, nullptr,
      qb, kb, vt, 4096, 3072, 1024, bigw ? 0 : 1, 1);
  // 2) RoPE in-place on q, k
  rope<<<dim3(512), 256, 0, stream>>>(qb, kb);
  // 3) causal flash attention
  if (bigs) {
    attn_split<<<dim3(1024, 2), 256, 0, stream>>>(qb, kb, vt, Opart, mlb);
    combine<<<dim3(4096), 64, 0, stream>>>(Opart, mlb, yb);
  } else {
    attn_full<<<dim3(1024), 256, 0, stream>>>(qb, kb, vt, yb);
  }
  // 4) out = y(bf16) @ w_proj^T -> f32
  gemm_bt<<<dim3(8, 32), 256, 0, stream>>>(
      yb, bigw ? (const void*)wpb : (const void*)w_proj, out,
      nullptr, nullptr, nullptr, 4096, 1024, 1024, bigw ? 0 : 1, 0);
}